// Round 2
// baseline (11995.712 us; speedup 1.0000x reference)
//
#include <hip/hip_runtime.h>
#include <stdint.h>

#define B_ 16
#define T_ 2048
#define I_ 512
#define H_ 512
#define NW 128         // single-wave workgroups; each owns 4 h-columns x 4 gates = 16 gate rows

typedef __bf16 bf16x8 __attribute__((ext_vector_type(8)));
typedef __bf16 bf16x4 __attribute__((ext_vector_type(4)));
typedef float  f32x4  __attribute__((ext_vector_type(4)));

__device__ __forceinline__ float sigm(float x) {
    return __builtin_amdgcn_rcpf(1.f + __builtin_amdgcn_exp2f(-1.44269504f * x));
}
__device__ __forceinline__ float tanh_f(float x) {
    float xc = fmaxf(x, -40.f);
    float e  = __builtin_amdgcn_exp2f(-2.88539008f * xc);
    return (1.f - e) * __builtin_amdgcn_rcpf(1.f + e);
}

// ---- prep: x [B][T][I] fp32 -> xp [T][B][I] bf16 ----
__global__ void pack_x(const float* __restrict__ x, __bf16* __restrict__ xp) {
    int q = blockIdx.x * 256 + threadIdx.x;   // 4 elems each
    int o = q * 4;
    int i  = o & (I_ - 1);
    int tb = o >> 9;
    int b  = tb & (B_ - 1);
    int t  = tb >> 4;
    float4 v = *(const float4*)(x + ((size_t)(b * T_ + t) * I_ + i));
    *(bf16x4*)(xp + o) = (bf16x4){(__bf16)v.x, (__bf16)v.y, (__bf16)v.z, (__bf16)v.w};
}

// ---- prep: per-WG weight pack. wp[w][n][k], n=0..15 (gate g=n>>2, local col cl=n&3),
//      global row = g*512 + w*4 + cl
__global__ void pack_w(const float* __restrict__ Wi, const float* __restrict__ Wh,
                       __bf16* __restrict__ wip, __bf16* __restrict__ whp) {
    int q = blockIdx.x * 256 + threadIdx.x;   // 2*128*16*128 threads, 4 k each
    int k = (q & 127) * 4;  q >>= 7;
    int n = q & 15;         q >>= 4;
    int w = q & 127;        q >>= 7;
    int mat = q;
    int row = (n >> 2) * 512 + w * 4 + (n & 3);
    const float* src = (mat ? Wh : Wi) + (size_t)row * 512 + k;
    float4 v = *(const float4*)src;
    __bf16* dst = (mat ? whp : wip) + ((size_t)(w * 16 + n) * 512 + k);
    *(bf16x4*)dst = (bf16x4){(__bf16)v.x, (__bf16)v.y, (__bf16)v.z, (__bf16)v.w};
}

// ---- prep: h0 -> hbuf[0] bf16; biasp[w*16+n] = bi[row]+bh[row]
__global__ void prep_small(const float* __restrict__ h0, const float* __restrict__ bi,
                           const float* __restrict__ bh, __bf16* __restrict__ hbuf,
                           float* __restrict__ biasp) {
    int i = blockIdx.x * 256 + threadIdx.x;   // 8192 threads
    hbuf[i] = (__bf16)h0[i];
    if (i < NW * 16) {
        int w = i >> 4, n = i & 15;
        int row = (n >> 2) * 512 + w * 4 + (n & 3);
        biasp[i] = bi[row] + bh[row];
    }
}

// ---- persistent recurrence: 128 WGs x 1 wave, no LDS, no __syncthreads ----
__global__ __launch_bounds__(64) void lstm_main(
    const float* __restrict__ c0,
    const __bf16* __restrict__ xp,
    const __bf16* __restrict__ wip,
    const __bf16* __restrict__ whp,
    const float* __restrict__ biasp,
    __bf16* hbuf,                 // [2][B_][H_]
    unsigned* flags,              // [NW] monotone step counters
    float* __restrict__ out)
{
    const int w    = blockIdx.x;
    const int lane = threadIdx.x;
    const int quad = lane >> 4;
    const int n16  = lane & 15;

    // persistent weight fragments (B-operand: lane = gate row n, k = kc*32 + quad*8 + j)
    bf16x8 bwx[16], bwh[16];
#pragma unroll
    for (int kc = 0; kc < 16; ++kc) {
        size_t idx = ((size_t)(w * 16 + n16)) * 512 + kc * 32 + quad * 8;
        bwx[kc] = *(const bf16x8*)(wip + idx);
        bwh[kc] = *(const bf16x8*)(whp + idx);
    }
    const float bias = biasp[w * 16 + n16];
    const int col = w * 4 + n16;          // valid when n16 < 4
    float creg[4];
    if (n16 < 4)
#pragma unroll
        for (int r = 0; r < 4; ++r)
            creg[r] = c0[(size_t)(quad * 4 + r) * H_ + col];

    float* outHT = out + (size_t)B_ * T_ * H_;
    float* outCT = outHT + (size_t)B_ * H_;

    for (int t = 0; t < T_; ++t) {
        // ---- x-side partial (independent of h; overlaps producer latency) ----
        f32x4 accA = {0.f, 0.f, 0.f, 0.f}, accB = {0.f, 0.f, 0.f, 0.f};
        {
            const __bf16* xt = xp + (size_t)t * (B_ * I_);
            bf16x8 ax[16];
#pragma unroll
            for (int kc = 0; kc < 16; ++kc)
                ax[kc] = *(const bf16x8*)(xt + (size_t)n16 * I_ + kc * 32 + quad * 8);
#pragma unroll
            for (int kc = 0; kc < 8; ++kc) {
                accA = __builtin_amdgcn_mfma_f32_16x16x32_bf16(ax[kc],     bwx[kc],     accA, 0, 0, 0);
                accB = __builtin_amdgcn_mfma_f32_16x16x32_bf16(ax[kc + 8], bwx[kc + 8], accB, 0, 0, 0);
            }
        }

        // ---- wait for h_t (all producers' flags >= t) ----
        if (t > 0) {
            for (;;) {
                unsigned f0 = __hip_atomic_load(flags + lane,      __ATOMIC_RELAXED, __HIP_MEMORY_SCOPE_AGENT);
                unsigned f1 = __hip_atomic_load(flags + 64 + lane, __ATOMIC_RELAXED, __HIP_MEMORY_SCOPE_AGENT);
                if (__all(f0 >= (unsigned)t && f1 >= (unsigned)t)) break;
            }
        }

        // ---- h loads (A-operand: lane = batch m, k = kc*32 + quad*8 + j) ----
        const unsigned long long* hr64 =
            (const unsigned long long*)(hbuf + (size_t)(t & 1) * (B_ * H_));
        unsigned long long hu[32];
#pragma unroll
        for (int kc = 0; kc < 16; ++kc) {
            size_t e = ((size_t)n16 * H_ + kc * 32 + quad * 8) >> 2;
            hu[2 * kc]     = __hip_atomic_load(hr64 + e,     __ATOMIC_RELAXED, __HIP_MEMORY_SCOPE_AGENT);
            hu[2 * kc + 1] = __hip_atomic_load(hr64 + e + 1, __ATOMIC_RELAXED, __HIP_MEMORY_SCOPE_AGENT);
        }
#pragma unroll
        for (int kc = 0; kc < 8; ++kc) {
            union { unsigned long long u[2]; bf16x8 v; } a0, a1;
            a0.u[0] = hu[2 * kc];      a0.u[1] = hu[2 * kc + 1];
            a1.u[0] = hu[2 * kc + 16]; a1.u[1] = hu[2 * kc + 17];
            accA = __builtin_amdgcn_mfma_f32_16x16x32_bf16(a0.v, bwh[kc],     accA, 0, 0, 0);
            accB = __builtin_amdgcn_mfma_f32_16x16x32_bf16(a1.v, bwh[kc + 8], accB, 0, 0, 0);
        }
        f32x4 acc = accA + accB;

        // ---- activations: D[row=quad*4+r (batch)][col=n16 (gate row)] ----
        unsigned short* hw16 =
            (unsigned short*)(hbuf + (size_t)((t + 1) & 1) * (B_ * H_));
        float hv[4], cv[4];
#pragma unroll
        for (int r = 0; r < 4; ++r) {
            float pre = acc[r] + bias;
            float a = ((n16 >> 2) == 2) ? tanh_f(pre) : sigm(pre);   // gate g = n16>>2: 2 = cell
            float fg = __shfl_xor(a, 4, 64);
            float gg = __shfl_xor(a, 8, 64);
            float og = __shfl_xor(a, 12, 64);
            if (n16 < 4) {                                           // canonical lanes: gate i
                float c = fg * creg[r] + a * gg;
                creg[r] = c;
                float h = og * tanh_f(c);
                hv[r] = h; cv[r] = c;
                __bf16 hb = (__bf16)h;
                __hip_atomic_store(hw16 + (quad * 4 + r) * H_ + col,
                                   __builtin_bit_cast(unsigned short, hb),
                                   __ATOMIC_RELAXED, __HIP_MEMORY_SCOPE_AGENT);
            }
        }

        // ---- publish (release drains the h stores), then out[] off critical path ----
        if (lane == 0)
            __hip_atomic_store(flags + w, (unsigned)(t + 1),
                               __ATOMIC_RELEASE, __HIP_MEMORY_SCOPE_AGENT);
        if (n16 < 4) {
#pragma unroll
            for (int r = 0; r < 4; ++r) {
                int m = quad * 4 + r;
                out[((size_t)m * T_ + t) * H_ + col] = hv[r];
                if (t == T_ - 1) {
                    outHT[(size_t)m * H_ + col] = hv[r];
                    outCT[(size_t)m * H_ + col] = cv[r];
                }
            }
        }
    }
}

extern "C" void kernel_launch(void* const* d_in, const int* in_sizes, int n_in,
                              void* d_out, int out_size, void* d_ws, size_t ws_size,
                              hipStream_t stream) {
    const float* x  = (const float*)d_in[0];
    const float* h0 = (const float*)d_in[1];
    const float* c0 = (const float*)d_in[2];
    const float* Wi = (const float*)d_in[3];
    const float* bi = (const float*)d_in[4];
    const float* Wh = (const float*)d_in[5];
    const float* bh = (const float*)d_in[6];
    float* out = (float*)d_out;

    char* ws = (char*)d_ws;
    __bf16*   xp    = (__bf16*)ws;                                   // 32 MB
    __bf16*   wip   = (__bf16*)(ws + 33554432);                      // 2 MB
    __bf16*   whp   = (__bf16*)(ws + 35651584);                      // 2 MB
    float*    biasp = (float*) (ws + 37748736);                      // 8 KB
    __bf16*   hbuf  = (__bf16*)(ws + 37756928);                      // 2 x 16 KB
    unsigned* flags = (unsigned*)(ws + 37789696);                    // 512 B

    hipMemsetAsync(flags, 0, 512, stream);
    pack_x<<<16384, 256, 0, stream>>>(x, xp);
    pack_w<<<2048, 256, 0, stream>>>(Wi, Wh, wip, whp);
    prep_small<<<32, 256, 0, stream>>>(h0, bi, bh, hbuf, biasp);

    void* args[] = { (void*)&c0, (void*)&xp, (void*)&wip, (void*)&whp, (void*)&biasp,
                     (void*)&hbuf, (void*)&flags, (void*)&out };
    hipLaunchCooperativeKernel((void*)lstm_main, dim3(NW), dim3(64), args, 0, stream);
}